// Round 6
// baseline (263.622 us; speedup 1.0000x reference)
//
#include <hip/hip_runtime.h>
#include <hip/hip_bf16.h>
#include <float.h>

// Problem constants (B,H,W,D,K) = (16,32,32,256,8192)
#define NROWS 16384
#define DDIM  256
#define KCB   8192
#define ZQ_ELEMS 4194304

// ws layout (~4.3 MB)
#define WS_ESQ_OFF   0                      // float[8192]
#define WS_ZSQ_OFF   32768                  // float[16384]
#define WS_CAND_OFF  98304                  // u32[16384*64] = 4 MB
#define WS_PART_OFF  (98304 + 4194304)      // float[4096]
// bf16 copies of z/cb live in d_out scratch (overwritten later by outputs)

#define QWINDOW 410   // rescore window: 0.025 in 1/16384 fixed-point quanta

typedef __attribute__((ext_vector_type(8))) short short8;
typedef __attribute__((ext_vector_type(4))) float floatx4;

__device__ __forceinline__ unsigned short bf16_rn(float f) {
    unsigned u = __float_as_uint(f);
    return (unsigned short)((u + 0x7FFFu + ((u >> 16) & 1u)) >> 16);
}

// async global->LDS DMA, 16 B per lane; LDS dest = wave-uniform base + lane*16
__device__ __forceinline__ void gload_lds16(const void* g, void* l) {
    __builtin_amdgcn_global_load_lds(
        (const __attribute__((address_space(1))) void*)(uintptr_t)g,
        (__attribute__((address_space(3))) void*)(unsigned)(uintptr_t)l, 16, 0, 0);
}

// ---------- prep: bf16 convert + numpy-pairwise sumsq (bit-exact, proven) ----
__global__ __launch_bounds__(256) void prep_kernel(
    const float* __restrict__ z, const float* __restrict__ cb,
    unsigned short* __restrict__ z16, unsigned short* __restrict__ cb16,
    float* __restrict__ esq, float* __restrict__ zsq) {
#pragma clang fp contract(off)
    int tid = threadIdx.x;
    int rowb = tid >> 2, sub = tid & 3;
    int b = sub >> 1, jq = sub & 1;
    int row = blockIdx.x * 64 + rowb;
    const float* src; unsigned short* dst; float* o;
    if (row < KCB) { src = cb + (size_t)row * DDIM; dst = cb16 + (size_t)row * DDIM; o = esq + row; }
    else { int r = row - KCB; src = z + (size_t)r * DDIM; dst = z16 + (size_t)r * DDIM; o = zsq + r; }
    float r0 = 0.f, r1 = 0.f, r2 = 0.f, r3 = 0.f;
    for (int t = 0; t < 16; ++t) {
        int off = b * 128 + t * 8 + jq * 4;
        float4 v = *(const float4*)(src + off);
        float q0 = v.x * v.x, q1 = v.y * v.y, q2 = v.z * v.z, q3 = v.w * v.w;
        r0 = r0 + q0; r1 = r1 + q1; r2 = r2 + q2; r3 = r3 + q3;
        ushort4 w;
        w.x = bf16_rn(v.x); w.y = bf16_rn(v.y); w.z = bf16_rn(v.z); w.w = bf16_rn(v.w);
        *(ushort4*)(dst + off) = w;
    }
    float s = (r0 + r1) + (r2 + r3);
    s = s + __shfl_xor(s, 1);   // jq pair
    s = s + __shfl_xor(s, 2);   // block pair
    if (sub == 0) *o = s;
}

// ---------- bf16 MFMA filter: block = 128 z-rows x 256 cols ----------
// A(z) 128x256 staged ONCE via global_load_lds (XOR source swizzle; 2-way bank
// alias only = free). B goes global->VGPR directly, double-buffered one K-step
// ahead: fine-grained vmcnt pipelining, a single __syncthreads in the kernel.
// Wave = 128 rows x 64 cols: 8 m-tiles x 4 n-tiles of 16x16, acc = 128 VGPR.
__global__ __launch_bounds__(256, 2) void gemm_filter_kernel(
    const unsigned short* __restrict__ z16, const unsigned short* __restrict__ cb16,
    const float* __restrict__ esq, unsigned* __restrict__ cand) {
    __shared__ unsigned short As[128 * 256];  // 64 KB
    __shared__ unsigned st[128][4][2];        // 4 KB cross-wave top-2 merge

    const int tid = threadIdx.x;
    const int w = tid >> 6, lane = tid & 63;
    const int c = lane & 15, q = lane >> 4;
    const int m0 = blockIdx.x * 128;               // row block (fast grid dim -> XCD shares col panel)
    const int panel = blockIdx.y * 256 + w * 64;   // this wave's 64-col panel

    // stage A tile via async DMA (16 instrs/wave, 1 KB each)
#pragma unroll
    for (int p = 0; p < 16; ++p) {
        int s = (w * 16 + p) * 64 + lane;
        int row = s >> 5, jp = s & 31;
        int j = (jp & 24) | ((jp & 7) ^ (row & 7));   // source-addr XOR swizzle
        gload_lds16(z16 + (size_t)(m0 + row) * 256 + j * 8,
                    (char*)As + (w * 16 + p) * 1024);
    }

    // epilogue constants (overlap with DMA)
    float ekf[4];
#pragma unroll
    for (int nf = 0; nf < 4; ++nf)
        ekf[nf] = (esq[panel + nf * 16 + c] + 8.0f) * 16384.0f;   // (e_sq+8) in quanta

    const unsigned short* bbase = cb16 + ((size_t)(panel + c) << 8) + q * 8;

    floatx4 acc[8][4];
#pragma unroll
    for (int f = 0; f < 8; ++f)
#pragma unroll
        for (int nf = 0; nf < 4; ++nf) acc[f][nf] = (floatx4){0.f, 0.f, 0.f, 0.f};

    __syncthreads();   // the only barrier: A-DMA drained

    short8 bfA[4], bfB[4], af[8];
#pragma unroll
    for (int nf = 0; nf < 4; ++nf)
        bfA[nf] = *(const short8*)(bbase + nf * 4096);   // kk=0

#pragma unroll
    for (int kk = 0; kk < 8; kk += 2) {
        // prefetch kk+1 while computing kk
#pragma unroll
        for (int nf = 0; nf < 4; ++nf)
            bfB[nf] = *(const short8*)(bbase + nf * 4096 + (kk + 1) * 32);
#pragma unroll
        for (int f = 0; f < 8; ++f) {
            int row = f * 16 + c, jp = kk * 4 + q;
            af[f] = *(const short8*)((const char*)As + row * 512 +
                     ((jp & 24) | ((jp & 7) ^ (row & 7))) * 16);
        }
#pragma unroll
        for (int f = 0; f < 8; ++f)
#pragma unroll
            for (int nf = 0; nf < 4; ++nf)
                acc[f][nf] = __builtin_amdgcn_mfma_f32_16x16x32_bf16(
                    af[f], bfA[nf], acc[f][nf], 0, 0, 0);
        if (kk + 2 < 8) {
#pragma unroll
            for (int nf = 0; nf < 4; ++nf)
                bfA[nf] = *(const short8*)(bbase + nf * 4096 + (kk + 2) * 32);
        }
#pragma unroll
        for (int f = 0; f < 8; ++f) {
            int row = f * 16 + c, jp = (kk + 1) * 4 + q;
            af[f] = *(const short8*)((const char*)As + row * 512 +
                     ((jp & 24) | ((jp & 7) ^ (row & 7))) * 16);
        }
#pragma unroll
        for (int f = 0; f < 8; ++f)
#pragma unroll
            for (int nf = 0; nf < 4; ++nf)
                acc[f][nf] = __builtin_amdgcn_mfma_f32_16x16x32_bf16(
                    af[f], bfB[nf], acc[f][nf], 0, 0, 0);
    }

    // ---- epilogue: fixed-point pack + per-row top-2 over this wave's 64 cols
#pragma unroll
    for (int f = 0; f < 8; ++f)
#pragma unroll
        for (int r = 0; r < 4; ++r) {
            unsigned b1 = 0xFFFFFFFFu, b2 = 0xFFFFFFFFu;
#pragma unroll
            for (int nf = 0; nf < 4; ++nf) {
                float fx = fmaf(-32768.0f, acc[f][nf][r], ekf[nf]);
                unsigned p = ((unsigned)fx << 13) | (unsigned)(panel + nf * 16 + c);
                unsigned t = min(p, b2);
                b2 = max(t, b1);   // med3(p, b1, b2)
                b1 = min(b1, p);
            }
#pragma unroll
            for (int sft = 1; sft < 16; sft <<= 1) {
                unsigned o1 = __shfl_xor(b1, sft);
                unsigned o2 = __shfl_xor(b2, sft);
                unsigned mx = max(b1, o1);
                b1 = min(b1, o1);
                b2 = min(min(mx, b2), o2);
            }
            if (c == 0) {
                st[f * 16 + q * 4 + r][w][0] = b1;
                st[f * 16 + q * 4 + r][w][1] = b2;
            }
        }
    __syncthreads();
    if (tid < 128) {
        unsigned a1 = st[tid][0][0], a2 = st[tid][0][1];
#pragma unroll
        for (int ww = 1; ww < 4; ++ww) {
            unsigned p1 = st[tid][ww][0], p2 = st[tid][ww][1];
            unsigned mx = max(a1, p1);
            a1 = min(a1, p1);
            a2 = min(min(mx, a2), p2);
        }
        cand[(size_t)(m0 + tid) * 64 + blockIdx.y * 2 + 0] = a1;
        cand[(size_t)(m0 + tid) * 64 + blockIdx.y * 2 + 1] = a2;
    }
}

// ---------- resolve (numpy-replica fp32 rescore, proven) + gather ------------
__global__ __launch_bounds__(256) void resolve_gather_kernel(
    const float* __restrict__ z, const float* __restrict__ cb,
    const float* __restrict__ zsq, const float* __restrict__ esq,
    const unsigned* __restrict__ cand, float* __restrict__ out,
    float* __restrict__ partials) {
#pragma clang fp contract(off)
    __shared__ float wls[4];
    int w = threadIdx.x >> 6, l = threadIdx.x & 63;
    int row = blockIdx.x * 4 + w;
    unsigned p = cand[(size_t)row * 64 + l];
    unsigned m = p;
#pragma unroll
    for (int s = 32; s; s >>= 1) m = min(m, __shfl_xor(m, s));
    bool active = (p >> 13) <= (m >> 13) + QWINDOW;
    float dref = FLT_MAX; int k = 0x7FFFFFFF;
    if (active) {
        k = (int)(p & 8191u);
        const float* zr = z + (size_t)row * DDIM;
        const float* er = cb + (size_t)k * DDIM;
        float cacc = 0.f;
        for (int d = 0; d < DDIM; ++d)
            cacc = fmaf(zr[d], er[d], cacc);   // BLAS-style sequential-K fma chain
        float s1 = zsq[row] + esq[k];          // numpy: z_sq + e_sq (fp32 round)
        float two = 2.0f * cacc;               // exact
        dref = s1 - two;                       // single fp32 round
    }
#pragma unroll
    for (int s = 32; s; s >>= 1) {
        float od = __shfl_xor(dref, s);
        int ok = __shfl_xor(k, s);
        if (od < dref || (od == dref && ok < k)) { dref = od; k = ok; }
    }
    if (l == 0) out[ZQ_ELEMS + row] = (float)k;

    int d0 = l * 4;
    float4 e4 = *(const float4*)(cb + (size_t)k * DDIM + d0);
    float4 z4 = *(const float4*)(z + (size_t)row * DDIM + d0);
    float4 o4;
    o4.x = z4.x + (e4.x - z4.x); o4.y = z4.y + (e4.y - z4.y);
    o4.z = z4.z + (e4.z - z4.z); o4.w = z4.w + (e4.w - z4.w);
    *(float4*)(out + (size_t)row * DDIM + d0) = o4;
    float dx = z4.x - e4.x, dy = z4.y - e4.y, dz = z4.z - e4.z, dw = z4.w - e4.w;
    float ls = dx * dx;
    ls = fmaf(dy, dy, ls); ls = fmaf(dz, dz, ls); ls = fmaf(dw, dw, ls);
#pragma unroll
    for (int s = 32; s; s >>= 1) ls += __shfl_xor(ls, s);
    if (l == 0) wls[w] = ls;
    __syncthreads();
    if (threadIdx.x == 0)
        partials[blockIdx.x] = (wls[0] + wls[1]) + (wls[2] + wls[3]);
}

__global__ __launch_bounds__(256) void final_kernel(const float* __restrict__ partials,
                                                    float* __restrict__ out) {
    __shared__ double wd[4];
    int w = threadIdx.x >> 6, l = threadIdx.x & 63;
    double s = 0.0;
#pragma unroll
    for (int j = 0; j < 16; ++j) s += (double)partials[threadIdx.x + j * 256];
#pragma unroll
    for (int sh = 32; sh; sh >>= 1) s += __shfl_xor(s, sh);
    if (l == 0) wd[w] = s;
    __syncthreads();
    if (threadIdx.x == 0)
        out[ZQ_ELEMS + NROWS] =
            (float)(1.25 * ((wd[0] + wd[1]) + (wd[2] + wd[3])) / (double)ZQ_ELEMS);
}

extern "C" void kernel_launch(void* const* d_in, const int* in_sizes, int n_in,
                              void* d_out, int out_size, void* d_ws, size_t ws_size,
                              hipStream_t stream) {
    const float* z = (const float*)d_in[0];
    const float* cb = (const float*)d_in[1];
    float* out = (float*)d_out;
    char* ws = (char*)d_ws;
    float* esq = (float*)(ws + WS_ESQ_OFF);
    float* zsq = (float*)(ws + WS_ZSQ_OFF);
    unsigned* cand = (unsigned*)(ws + WS_CAND_OFF);
    float* partials = (float*)(ws + WS_PART_OFF);
    // bf16 scratch inside d_out (12 MB < 16.8 MB); overwritten by outputs later
    unsigned short* z16 = (unsigned short*)d_out;
    unsigned short* cb16 = z16 + (size_t)NROWS * DDIM;

    prep_kernel<<<dim3((KCB + NROWS) / 64), 256, 0, stream>>>(z, cb, z16, cb16, esq, zsq);
    gemm_filter_kernel<<<dim3(NROWS / 128, KCB / 256), 256, 0, stream>>>(z16, cb16, esq, cand);
    resolve_gather_kernel<<<dim3(NROWS / 4), 256, 0, stream>>>(z, cb, zsq, esq, cand, out, partials);
    final_kernel<<<1, 256, 0, stream>>>(partials, out);
}

// Round 7
// 245.776 us; speedup vs baseline: 1.0726x; 1.0726x over previous
//
#include <hip/hip_runtime.h>
#include <hip/hip_bf16.h>
#include <float.h>

// Problem constants (B,H,W,D,K) = (16,32,32,256,8192)
#define NROWS 16384
#define DDIM  256
#define KCB   8192
#define ZQ_ELEMS 4194304

// ws layout (~4.3 MB)
#define WS_ESQ_OFF   0                      // float[8192]
#define WS_ZSQ_OFF   32768                  // float[16384]
#define WS_CAND_OFF  98304                  // u32[16384*64] = 4 MB
#define WS_PART_OFF  (98304 + 4194304)      // float[4096]
// bf16 copies of z/cb live in d_out scratch (overwritten later by outputs)

#define QWINDOW 410   // rescore window: 0.025 in 1/16384 fixed-point quanta

typedef __attribute__((ext_vector_type(8))) short short8;
typedef __attribute__((ext_vector_type(4))) float floatx4;

__device__ __forceinline__ unsigned short bf16_rn(float f) {
    unsigned u = __float_as_uint(f);
    return (unsigned short)((u + 0x7FFFu + ((u >> 16) & 1u)) >> 16);
}

// async global->LDS DMA, 16 B per lane; LDS dest = wave-uniform base + lane*16
__device__ __forceinline__ void gload_lds16(const void* g, void* l) {
    __builtin_amdgcn_global_load_lds(
        (const __attribute__((address_space(1))) void*)(uintptr_t)g,
        (__attribute__((address_space(3))) void*)(unsigned)(uintptr_t)l, 16, 0, 0);
}

// top-2 insert: 3 ops (b1' = min; b2' = med3(p,b1,b2) via min/max)
__device__ __forceinline__ void ins2(unsigned& b1, unsigned& b2, unsigned p) {
    unsigned t = min(p, b2);
    b2 = max(t, b1);
    b1 = min(b1, p);
}

// ---------- prep: bf16 convert + numpy-pairwise sumsq (bit-exact, proven) ----
__global__ __launch_bounds__(256) void prep_kernel(
    const float* __restrict__ z, const float* __restrict__ cb,
    unsigned short* __restrict__ z16, unsigned short* __restrict__ cb16,
    float* __restrict__ esq, float* __restrict__ zsq) {
#pragma clang fp contract(off)
    int tid = threadIdx.x;
    int rowb = tid >> 2, sub = tid & 3;
    int b = sub >> 1, jq = sub & 1;
    int row = blockIdx.x * 64 + rowb;
    const float* src; unsigned short* dst; float* o;
    if (row < KCB) { src = cb + (size_t)row * DDIM; dst = cb16 + (size_t)row * DDIM; o = esq + row; }
    else { int r = row - KCB; src = z + (size_t)r * DDIM; dst = z16 + (size_t)r * DDIM; o = zsq + r; }
    float r0 = 0.f, r1 = 0.f, r2 = 0.f, r3 = 0.f;
    for (int t = 0; t < 16; ++t) {
        int off = b * 128 + t * 8 + jq * 4;
        float4 v = *(const float4*)(src + off);
        float q0 = v.x * v.x, q1 = v.y * v.y, q2 = v.z * v.z, q3 = v.w * v.w;
        r0 = r0 + q0; r1 = r1 + q1; r2 = r2 + q2; r3 = r3 + q3;
        ushort4 w;
        w.x = bf16_rn(v.x); w.y = bf16_rn(v.y); w.z = bf16_rn(v.z); w.w = bf16_rn(v.w);
        *(ushort4*)(dst + off) = w;
    }
    float s = (r0 + r1) + (r2 + r3);
    s = s + __shfl_xor(s, 1);   // jq pair
    s = s + __shfl_xor(s, 2);   // block pair
    if (sub == 0) *o = s;
}

// ---------- bf16 MFMA filter: block = 128 z-rows x 256 cols ----------
// A staged once via global_load_lds in MFMA-FRAGMENT order (each DMA instr
// gathers 16 full cache lines -> 1 contiguous KB): K-loop ds_read_b128 is
// base+lane*16, conflict-free. B global->VGPR, depth-2 prefetch (3 buffers).
// Epilogue: per-lane pack+top-2, u64 to LDS (reuses A buffer), flat scan.
__global__ __launch_bounds__(256, 2) void gemm_filter_kernel(
    const unsigned short* __restrict__ z16, const unsigned short* __restrict__ cb16,
    const float* __restrict__ esq, unsigned* __restrict__ cand) {
    __shared__ char sh[65536];                       // A frags, then top-2 state
    unsigned long long* st = (unsigned long long*)sh;

    const int tid = threadIdx.x;
    const int w = tid >> 6, lane = tid & 63;
    const int c = lane & 15, q = lane >> 4;
    const int m0 = blockIdx.x * 128;               // row block (fast grid dim)
    const int panel = blockIdx.y * 256 + w * 64;   // this wave's 64-col panel

    // stage A in fragment order: chunk ch=kk*8+f holds lane(q,c) ->
    // z16[row=f*16+c][d=kk*32+q*8 ..+7]  (16 B per lane, 16 lines per instr)
#pragma unroll
    for (int p = 0; p < 16; ++p) {
        int ch = w * 16 + p;
        int kk = ch >> 3, f = ch & 7;
        gload_lds16(z16 + (size_t)(m0 + f * 16 + c) * 256 + kk * 32 + q * 8,
                    sh + ch * 1024);
    }

    float ekf[4];
#pragma unroll
    for (int nf = 0; nf < 4; ++nf)
        ekf[nf] = (esq[panel + nf * 16 + c] + 8.0f) * 16384.0f;  // (e_sq+8) quanta

    const unsigned short* bbase = cb16 + ((size_t)(panel + c) << 8) + q * 8;

    floatx4 acc[8][4];
#pragma unroll
    for (int f = 0; f < 8; ++f)
#pragma unroll
        for (int nf = 0; nf < 4; ++nf) acc[f][nf] = (floatx4){0.f, 0.f, 0.f, 0.f};

    short8 bbuf[3][4];
#pragma unroll
    for (int nf = 0; nf < 4; ++nf)
        bbuf[0][nf] = *(const short8*)(bbase + nf * 4096);        // kk=0
#pragma unroll
    for (int nf = 0; nf < 4; ++nf)
        bbuf[1][nf] = *(const short8*)(bbase + nf * 4096 + 32);   // kk=1

    __syncthreads();   // A-DMA (and B preloads) drained

#pragma unroll
    for (int kk = 0; kk < 8; ++kk) {
        if (kk + 2 < 8) {
            int b = (kk + 2) % 3;
#pragma unroll
            for (int nf = 0; nf < 4; ++nf)
                bbuf[b][nf] = *(const short8*)(bbase + nf * 4096 + (kk + 2) * 32);
        }
        short8 af[8];
#pragma unroll
        for (int f = 0; f < 8; ++f)
            af[f] = *(const short8*)(sh + (kk * 8 + f) * 1024 + lane * 16);
        const int cur = kk % 3;
#pragma unroll
        for (int f = 0; f < 8; ++f)
#pragma unroll
            for (int nf = 0; nf < 4; ++nf)
                acc[f][nf] = __builtin_amdgcn_mfma_f32_16x16x32_bf16(
                    af[f], bbuf[cur][nf], acc[f][nf], 0, 0, 0);
    }

    __syncthreads();   // all waves done reading A frags; reuse sh as st

    // per-lane: rows f*16+q*4+r (32 rows) x cols nf*16+c (4 cols):
    // pack fixed-point key+index, keep top-2 over the 4 cols, one u64 to LDS
#pragma unroll
    for (int f = 0; f < 8; ++f)
#pragma unroll
        for (int r = 0; r < 4; ++r) {
            unsigned b1 = 0xFFFFFFFFu, b2 = 0xFFFFFFFFu;
#pragma unroll
            for (int nf = 0; nf < 4; ++nf) {
                float fx = fmaf(-32768.0f, acc[f][nf][r], ekf[nf]);
                unsigned p = ((unsigned)fx << 13) | (unsigned)(panel + nf * 16 + c);
                ins2(b1, b2, p);
            }
            int row = f * 16 + q * 4 + r;
            st[row * 64 + w * 16 + c] = ((unsigned long long)b2 << 32) | b1;
        }
    __syncthreads();

    // flat scan: thread t -> row t>>1, half t&1 (32 u64 = 64 u32 candidates)
    {
        int row = tid >> 1, h = tid & 1;
        unsigned b1 = 0xFFFFFFFFu, b2 = 0xFFFFFFFFu;
#pragma unroll
        for (int i = 0; i < 16; ++i) {
            int idx = (i + row) & 15;   // rotate to spread LDS banks
            uint4 v = *(const uint4*)&st[row * 64 + h * 32 + idx * 2];
            ins2(b1, b2, v.x); ins2(b1, b2, v.y);
            ins2(b1, b2, v.z); ins2(b1, b2, v.w);
        }
        unsigned o1 = __shfl_xor(b1, 1), o2 = __shfl_xor(b2, 1);
        unsigned mx = max(b1, o1);
        b1 = min(b1, o1);
        b2 = min(min(mx, b2), o2);
        if (h == 0) {
            uint2 res = {b1, b2};
            *(uint2*)&cand[(size_t)(m0 + row) * 64 + blockIdx.y * 2] = res;
        }
    }
}

// ---------- resolve (numpy-replica fp32 rescore, proven) + gather ------------
__global__ __launch_bounds__(256) void resolve_gather_kernel(
    const float* __restrict__ z, const float* __restrict__ cb,
    const float* __restrict__ zsq, const float* __restrict__ esq,
    const unsigned* __restrict__ cand, float* __restrict__ out,
    float* __restrict__ partials) {
#pragma clang fp contract(off)
    __shared__ float wls[4];
    int w = threadIdx.x >> 6, l = threadIdx.x & 63;
    int row = blockIdx.x * 4 + w;
    unsigned p = cand[(size_t)row * 64 + l];
    unsigned m = p;
#pragma unroll
    for (int s = 32; s; s >>= 1) m = min(m, __shfl_xor(m, s));
    bool active = (p >> 13) <= (m >> 13) + QWINDOW;
    float dref = FLT_MAX; int k = 0x7FFFFFFF;
    if (active) {
        k = (int)(p & 8191u);
        const float* zr = z + (size_t)row * DDIM;
        const float* er = cb + (size_t)k * DDIM;
        float cacc = 0.f;
        for (int t = 0; t < 64; ++t) {   // float4 loads, SAME sequential chain
            float4 zv = *(const float4*)(zr + t * 4);
            float4 ev = *(const float4*)(er + t * 4);
            cacc = fmaf(zv.x, ev.x, cacc);
            cacc = fmaf(zv.y, ev.y, cacc);
            cacc = fmaf(zv.z, ev.z, cacc);
            cacc = fmaf(zv.w, ev.w, cacc);
        }
        float s1 = zsq[row] + esq[k];   // numpy: z_sq + e_sq (fp32 round)
        float two = 2.0f * cacc;        // exact
        dref = s1 - two;                // single fp32 round
    }
#pragma unroll
    for (int s = 32; s; s >>= 1) {
        float od = __shfl_xor(dref, s);
        int ok = __shfl_xor(k, s);
        if (od < dref || (od == dref && ok < k)) { dref = od; k = ok; }
    }
    if (l == 0) out[ZQ_ELEMS + row] = (float)k;

    int d0 = l * 4;
    float4 e4 = *(const float4*)(cb + (size_t)k * DDIM + d0);
    float4 z4 = *(const float4*)(z + (size_t)row * DDIM + d0);
    float4 o4;
    o4.x = z4.x + (e4.x - z4.x); o4.y = z4.y + (e4.y - z4.y);
    o4.z = z4.z + (e4.z - z4.z); o4.w = z4.w + (e4.w - z4.w);
    *(float4*)(out + (size_t)row * DDIM + d0) = o4;
    float dx = z4.x - e4.x, dy = z4.y - e4.y, dz = z4.z - e4.z, dw = z4.w - e4.w;
    float ls = dx * dx;
    ls = fmaf(dy, dy, ls); ls = fmaf(dz, dz, ls); ls = fmaf(dw, dw, ls);
#pragma unroll
    for (int s = 32; s; s >>= 1) ls += __shfl_xor(ls, s);
    if (l == 0) wls[w] = ls;
    __syncthreads();
    if (threadIdx.x == 0)
        partials[blockIdx.x] = (wls[0] + wls[1]) + (wls[2] + wls[3]);
}

__global__ __launch_bounds__(256) void final_kernel(const float* __restrict__ partials,
                                                    float* __restrict__ out) {
    __shared__ double wd[4];
    int w = threadIdx.x >> 6, l = threadIdx.x & 63;
    double s = 0.0;
#pragma unroll
    for (int j = 0; j < 16; ++j) s += (double)partials[threadIdx.x + j * 256];
#pragma unroll
    for (int sh = 32; sh; sh >>= 1) s += __shfl_xor(s, sh);
    if (l == 0) wd[w] = s;
    __syncthreads();
    if (threadIdx.x == 0)
        out[ZQ_ELEMS + NROWS] =
            (float)(1.25 * ((wd[0] + wd[1]) + (wd[2] + wd[3])) / (double)ZQ_ELEMS);
}

extern "C" void kernel_launch(void* const* d_in, const int* in_sizes, int n_in,
                              void* d_out, int out_size, void* d_ws, size_t ws_size,
                              hipStream_t stream) {
    const float* z = (const float*)d_in[0];
    const float* cb = (const float*)d_in[1];
    float* out = (float*)d_out;
    char* ws = (char*)d_ws;
    float* esq = (float*)(ws + WS_ESQ_OFF);
    float* zsq = (float*)(ws + WS_ZSQ_OFF);
    unsigned* cand = (unsigned*)(ws + WS_CAND_OFF);
    float* partials = (float*)(ws + WS_PART_OFF);
    // bf16 scratch inside d_out (12 MB < 16.8 MB); overwritten by outputs later
    unsigned short* z16 = (unsigned short*)d_out;
    unsigned short* cb16 = z16 + (size_t)NROWS * DDIM;

    prep_kernel<<<dim3((KCB + NROWS) / 64), 256, 0, stream>>>(z, cb, z16, cb16, esq, zsq);
    gemm_filter_kernel<<<dim3(NROWS / 128, KCB / 256), 256, 0, stream>>>(z16, cb16, esq, cand);
    resolve_gather_kernel<<<dim3(NROWS / 4), 256, 0, stream>>>(z, cb, zsq, esq, cand, out, partials);
    final_kernel<<<1, 256, 0, stream>>>(partials, out);
}